// Round 12
// baseline (100.077 us; speedup 1.0000x reference)
//
#include <hip/hip_runtime.h>

// GlobalAttentionPooling — one wave per segment, 8-row groups, depth-2 pipe.
// x: [N,256] f32, batch: [N] int (sorted), W: [256,1] f32, b: [1] f32
// out: [NSEG,256] f32
//
// Kernel 1 builds seg_start[s] in d_ws (one coalesced pass over batch).
// Kernel 2: ONE WAVE (64-thread block) per segment; 4096 blocks = 16 waves/CU,
// entire grid resident from t=0. Lane l holds cols 4l..4l+3 (f32x4).
// gate = dot(x_i, W) (bias cancels in softmax ratio); exp without
// max-subtraction is exact-equivalent (gate ~ N(0,1), fp32-safe).
// x is read exactly once: ~524 MB, memory-bound.
//
// R12 vs R11 (96.4 us): group widened 4 -> 8 rows, still depth-2 pipeline.
// Rationale: the c=p rotation forces a vmcnt drain every group, so in-flight
// depth oscillated 0->4 loads; 8-row groups keep 16 KB/wave in flight at the
// drain point and halve loop-control overhead per byte. 8 independent
// shuffle-reduce chains interleave for ILP. All arrays fully unrolled
// (static indices -> registers, ~105 VGPR < 128 budget at 4 waves/SIMD).

typedef float f32x4 __attribute__((ext_vector_type(4)));

__global__ void seg_bounds_kernel(const int* __restrict__ batch,
                                  int* __restrict__ seg_start,
                                  int n_nodes, int n_seg)
{
    const int i = blockIdx.x * blockDim.x + threadIdx.x;
    if (i >= n_nodes) return;
    const int cur  = batch[i];
    const int prev = (i == 0) ? -1 : batch[i - 1];
    for (int s = prev + 1; s <= cur; ++s) seg_start[s] = i;
    if (i == n_nodes - 1) {
        for (int s = cur + 1; s <= n_seg; ++s) seg_start[s] = n_nodes;
    }
}

__global__ __launch_bounds__(64, 4)
void gap_wave(const float* __restrict__ x,
              const int* __restrict__ seg_start,
              const float* __restrict__ W,
              float* __restrict__ out)
{
    const int seg   = blockIdx.x;
    const int start = seg_start[seg];
    const int end   = seg_start[seg + 1];
    const int lane  = threadIdx.x;           // one wave per block

    const f32x4 wv = reinterpret_cast<const f32x4*>(W)[lane];
    const f32x4* __restrict__ xv = reinterpret_cast<const f32x4*>(x);

    f32x4 acc = {0.f, 0.f, 0.f, 0.f};
    float den = 0.f;

    constexpr int U = 8;                      // rows per group
    int base = start;
    if (base < end) {
        const int last = end - 1;

        f32x4 c0, c1, c2, c3, c4, c5, c6, c7;
        // prologue: first group (clamped rows predicated out via e=0)
        {
            const int r1 = (base + 1 <= last) ? base + 1 : last;
            const int r2 = (base + 2 <= last) ? base + 2 : last;
            const int r3 = (base + 3 <= last) ? base + 3 : last;
            const int r4 = (base + 4 <= last) ? base + 4 : last;
            const int r5 = (base + 5 <= last) ? base + 5 : last;
            const int r6 = (base + 6 <= last) ? base + 6 : last;
            const int r7 = (base + 7 <= last) ? base + 7 : last;
            c0 = __builtin_nontemporal_load(&xv[(size_t)base * 64 + lane]);
            c1 = __builtin_nontemporal_load(&xv[(size_t)r1   * 64 + lane]);
            c2 = __builtin_nontemporal_load(&xv[(size_t)r2   * 64 + lane]);
            c3 = __builtin_nontemporal_load(&xv[(size_t)r3   * 64 + lane]);
            c4 = __builtin_nontemporal_load(&xv[(size_t)r4   * 64 + lane]);
            c5 = __builtin_nontemporal_load(&xv[(size_t)r5   * 64 + lane]);
            c6 = __builtin_nontemporal_load(&xv[(size_t)r6   * 64 + lane]);
            c7 = __builtin_nontemporal_load(&xv[(size_t)r7   * 64 + lane]);
        }

        while (true) {
            const int next = base + U;
            const bool havenext = next <= last;

            // issue next group's loads before the dependent chain
            f32x4 p0, p1, p2, p3, p4, p5, p6, p7;
            if (havenext) {
                const int q1 = (next + 1 <= last) ? next + 1 : last;
                const int q2 = (next + 2 <= last) ? next + 2 : last;
                const int q3 = (next + 3 <= last) ? next + 3 : last;
                const int q4 = (next + 4 <= last) ? next + 4 : last;
                const int q5 = (next + 5 <= last) ? next + 5 : last;
                const int q6 = (next + 6 <= last) ? next + 6 : last;
                const int q7 = (next + 7 <= last) ? next + 7 : last;
                p0 = __builtin_nontemporal_load(&xv[(size_t)next * 64 + lane]);
                p1 = __builtin_nontemporal_load(&xv[(size_t)q1   * 64 + lane]);
                p2 = __builtin_nontemporal_load(&xv[(size_t)q2   * 64 + lane]);
                p3 = __builtin_nontemporal_load(&xv[(size_t)q3   * 64 + lane]);
                p4 = __builtin_nontemporal_load(&xv[(size_t)q4   * 64 + lane]);
                p5 = __builtin_nontemporal_load(&xv[(size_t)q5   * 64 + lane]);
                p6 = __builtin_nontemporal_load(&xv[(size_t)q6   * 64 + lane]);
                p7 = __builtin_nontemporal_load(&xv[(size_t)q7   * 64 + lane]);
            }

            float d0 = c0.x * wv.x + c0.y * wv.y + c0.z * wv.z + c0.w * wv.w;
            float d1 = c1.x * wv.x + c1.y * wv.y + c1.z * wv.z + c1.w * wv.w;
            float d2 = c2.x * wv.x + c2.y * wv.y + c2.z * wv.z + c2.w * wv.w;
            float d3 = c3.x * wv.x + c3.y * wv.y + c3.z * wv.z + c3.w * wv.w;
            float d4 = c4.x * wv.x + c4.y * wv.y + c4.z * wv.z + c4.w * wv.w;
            float d5 = c5.x * wv.x + c5.y * wv.y + c5.z * wv.z + c5.w * wv.w;
            float d6 = c6.x * wv.x + c6.y * wv.y + c6.z * wv.z + c6.w * wv.w;
            float d7 = c7.x * wv.x + c7.y * wv.y + c7.z * wv.z + c7.w * wv.w;

#pragma unroll
            for (int off = 32; off >= 1; off >>= 1) {
                d0 += __shfl_xor(d0, off, 64);
                d1 += __shfl_xor(d1, off, 64);
                d2 += __shfl_xor(d2, off, 64);
                d3 += __shfl_xor(d3, off, 64);
                d4 += __shfl_xor(d4, off, 64);
                d5 += __shfl_xor(d5, off, 64);
                d6 += __shfl_xor(d6, off, 64);
                d7 += __shfl_xor(d7, off, 64);
            }

            const float e0 = __expf(d0);
            const float e1 = (base + 1 <= last) ? __expf(d1) : 0.f;
            const float e2 = (base + 2 <= last) ? __expf(d2) : 0.f;
            const float e3 = (base + 3 <= last) ? __expf(d3) : 0.f;
            const float e4 = (base + 4 <= last) ? __expf(d4) : 0.f;
            const float e5 = (base + 5 <= last) ? __expf(d5) : 0.f;
            const float e6 = (base + 6 <= last) ? __expf(d6) : 0.f;
            const float e7 = (base + 7 <= last) ? __expf(d7) : 0.f;

            den += ((e0 + e1) + (e2 + e3)) + ((e4 + e5) + (e6 + e7));
            acc.x += (e0 * c0.x + e1 * c1.x + e2 * c2.x + e3 * c3.x)
                   + (e4 * c4.x + e5 * c5.x + e6 * c6.x + e7 * c7.x);
            acc.y += (e0 * c0.y + e1 * c1.y + e2 * c2.y + e3 * c3.y)
                   + (e4 * c4.y + e5 * c5.y + e6 * c6.y + e7 * c7.y);
            acc.z += (e0 * c0.z + e1 * c1.z + e2 * c2.z + e3 * c3.z)
                   + (e4 * c4.z + e5 * c5.z + e6 * c6.z + e7 * c7.z);
            acc.w += (e0 * c0.w + e1 * c1.w + e2 * c2.w + e3 * c3.w)
                   + (e4 * c4.w + e5 * c5.w + e6 * c6.w + e7 * c7.w);

            if (!havenext) break;
            c0 = p0; c1 = p1; c2 = p2; c3 = p3;
            c4 = p4; c5 = p5; c6 = p6; c7 = p7;
            base = next;
        }
    }

    // epilogue: all lanes hold the full den (post-butterfly); divide & store.
    f32x4 r;
    if (end > start) {
        const float inv = 1.0f / den;
        r.x = acc.x * inv; r.y = acc.y * inv; r.z = acc.z * inv; r.w = acc.w * inv;
    } else {
        r.x = 0.f; r.y = 0.f; r.z = 0.f; r.w = 0.f;
    }
    __builtin_nontemporal_store(r, &reinterpret_cast<f32x4*>(out)[(size_t)seg * 64 + lane]);
}

extern "C" void kernel_launch(void* const* d_in, const int* in_sizes, int n_in,
                              void* d_out, int out_size, void* d_ws, size_t ws_size,
                              hipStream_t stream) {
    const float* x     = (const float*)d_in[0];
    const int*   batch = (const int*)d_in[1];
    const float* W     = (const float*)d_in[2];
    float* out = (float*)d_out;

    const int n_nodes = in_sizes[1];        // batch element count
    const int n_seg   = out_size / 256;     // D = 256

    int* seg_start = (int*)d_ws;            // NSEG+1 ints

    seg_bounds_kernel<<<(n_nodes + 255) / 256, 256, 0, stream>>>(batch, seg_start, n_nodes, n_seg);
    gap_wave<<<n_seg, 64, 0, stream>>>(x, seg_start, W, out);
}

// Round 13
// 96.154 us; speedup vs baseline: 1.0408x; 1.0408x over previous
//
#include <hip/hip_runtime.h>

// GlobalAttentionPooling — one wave per segment, depth-2 pipeline, clean tail.
// x: [N,256] f32, batch: [N] int (sorted), W: [256,1] f32, b: [1] f32
// out: [NSEG,256] f32
//
// Kernel 1 builds seg_start[s] in d_ws (one coalesced pass over batch).
// Kernel 2: ONE WAVE (64-thread block) per segment; 4096 blocks = 16 waves/CU,
// entire grid resident from t=0 (no scheduling rounds, no churn, no LDS).
// Lane l holds cols 4l..4l+3 (f32x4). gate = dot(x_i, W) (bias cancels in
// softmax ratio); exp without max-subtraction is exact-equivalent here
// (gate ~ N(0,1), fp32-safe). x read exactly once: ~524 MB, memory-bound.
//
// History: R9 95.3 (4-wave blocks), R11 96.4 (1-wave), R12 100.1 (8-row
// groups — VGPR/VALU overhead regressed). This round: R11 structure with a
// clamp-free steady-state body (full 4-row groups, no cndmask chains, no
// duplicate clamped loads) + separate <=3-row tail loop.

typedef float f32x4 __attribute__((ext_vector_type(4)));

__global__ void seg_bounds_kernel(const int* __restrict__ batch,
                                  int* __restrict__ seg_start,
                                  int n_nodes, int n_seg)
{
    const int i = blockIdx.x * blockDim.x + threadIdx.x;
    if (i >= n_nodes) return;
    const int cur  = batch[i];
    const int prev = (i == 0) ? -1 : batch[i - 1];
    for (int s = prev + 1; s <= cur; ++s) seg_start[s] = i;
    if (i == n_nodes - 1) {
        for (int s = cur + 1; s <= n_seg; ++s) seg_start[s] = n_nodes;
    }
}

__global__ __launch_bounds__(64, 4)
void gap_wave(const float* __restrict__ x,
              const int* __restrict__ seg_start,
              const float* __restrict__ W,
              float* __restrict__ out)
{
    const int seg   = blockIdx.x;
    const int start = seg_start[seg];
    const int end   = seg_start[seg + 1];
    const int lane  = threadIdx.x;           // one wave per block

    const f32x4 wv = reinterpret_cast<const f32x4*>(W)[lane];
    const f32x4* __restrict__ xv = reinterpret_cast<const f32x4*>(x);

    f32x4 acc = {0.f, 0.f, 0.f, 0.f};
    float den = 0.f;

    const int n    = end - start;
    const int fend = start + (n & ~3);       // end of full 4-row groups

    // ---- steady state: full 4-row groups, clamp-free, depth-2 pipeline ----
    if (start < fend) {
        int base = start;
        f32x4 c0 = __builtin_nontemporal_load(&xv[(size_t)(base + 0) * 64 + lane]);
        f32x4 c1 = __builtin_nontemporal_load(&xv[(size_t)(base + 1) * 64 + lane]);
        f32x4 c2 = __builtin_nontemporal_load(&xv[(size_t)(base + 2) * 64 + lane]);
        f32x4 c3 = __builtin_nontemporal_load(&xv[(size_t)(base + 3) * 64 + lane]);

        while (true) {
            const int next = base + 4;
            const bool havenext = next < fend;

            // issue next group's loads before the dependent chain
            f32x4 p0, p1, p2, p3;
            if (havenext) {
                p0 = __builtin_nontemporal_load(&xv[(size_t)(next + 0) * 64 + lane]);
                p1 = __builtin_nontemporal_load(&xv[(size_t)(next + 1) * 64 + lane]);
                p2 = __builtin_nontemporal_load(&xv[(size_t)(next + 2) * 64 + lane]);
                p3 = __builtin_nontemporal_load(&xv[(size_t)(next + 3) * 64 + lane]);
            }

            float d0 = c0.x * wv.x + c0.y * wv.y + c0.z * wv.z + c0.w * wv.w;
            float d1 = c1.x * wv.x + c1.y * wv.y + c1.z * wv.z + c1.w * wv.w;
            float d2 = c2.x * wv.x + c2.y * wv.y + c2.z * wv.z + c2.w * wv.w;
            float d3 = c3.x * wv.x + c3.y * wv.y + c3.z * wv.z + c3.w * wv.w;

#pragma unroll
            for (int off = 32; off >= 1; off >>= 1) {
                d0 += __shfl_xor(d0, off, 64);
                d1 += __shfl_xor(d1, off, 64);
                d2 += __shfl_xor(d2, off, 64);
                d3 += __shfl_xor(d3, off, 64);
            }

            const float e0 = __expf(d0);
            const float e1 = __expf(d1);
            const float e2 = __expf(d2);
            const float e3 = __expf(d3);

            den   += (e0 + e1) + (e2 + e3);
            acc.x += e0 * c0.x + e1 * c1.x + e2 * c2.x + e3 * c3.x;
            acc.y += e0 * c0.y + e1 * c1.y + e2 * c2.y + e3 * c3.y;
            acc.z += e0 * c0.z + e1 * c1.z + e2 * c2.z + e3 * c3.z;
            acc.w += e0 * c0.w + e1 * c1.w + e2 * c2.w + e3 * c3.w;

            if (!havenext) break;
            c0 = p0; c1 = p1; c2 = p2; c3 = p3;
            base = next;
        }
    }

    // ---- tail: up to 3 rows ----
    for (int row = fend; row < end; ++row) {
        const f32x4 v = __builtin_nontemporal_load(&xv[(size_t)row * 64 + lane]);
        float d = v.x * wv.x + v.y * wv.y + v.z * wv.z + v.w * wv.w;
#pragma unroll
        for (int off = 32; off >= 1; off >>= 1) d += __shfl_xor(d, off, 64);
        const float e = __expf(d);
        den += e;
        acc.x += e * v.x; acc.y += e * v.y; acc.z += e * v.z; acc.w += e * v.w;
    }

    // epilogue: all lanes hold full den (post-butterfly); divide & store.
    f32x4 r;
    if (end > start) {
        const float inv = 1.0f / den;
        r.x = acc.x * inv; r.y = acc.y * inv; r.z = acc.z * inv; r.w = acc.w * inv;
    } else {
        r.x = 0.f; r.y = 0.f; r.z = 0.f; r.w = 0.f;
    }
    __builtin_nontemporal_store(r, &reinterpret_cast<f32x4*>(out)[(size_t)seg * 64 + lane]);
}

extern "C" void kernel_launch(void* const* d_in, const int* in_sizes, int n_in,
                              void* d_out, int out_size, void* d_ws, size_t ws_size,
                              hipStream_t stream) {
    const float* x     = (const float*)d_in[0];
    const int*   batch = (const int*)d_in[1];
    const float* W     = (const float*)d_in[2];
    float* out = (float*)d_out;

    const int n_nodes = in_sizes[1];        // batch element count
    const int n_seg   = out_size / 256;     // D = 256

    int* seg_start = (int*)d_ws;            // NSEG+1 ints

    seg_bounds_kernel<<<(n_nodes + 255) / 256, 256, 0, stream>>>(batch, seg_start, n_nodes, n_seg);
    gap_wave<<<n_seg, 64, 0, stream>>>(x, seg_start, W, out);
}